// Round 1
// baseline (454.429 us; speedup 1.0000x reference)
//
#include <hip/hip_runtime.h>
#include <math.h>

// GMM per-pixel sampling: out = mu[k] + exp(log_std[k]) * eps,
// k = #(cdf < u), cdf = cumsum(softmax(pi_logits)) over K=10 (innermost).
// Shapes [B,F,T,K] = [16,256,1024,10]; rows are 40 B.
//
// R3 structure: FULLY STREAMED. R2 gathered mu[k]/log_std[k] after the
// softmax -> dependent scattered loads; counters showed latency-bound
// (VALUBusy 22%, HBM 24%, both idle). Here we stream mu and log_std rows
// with the same affine float4 pattern as pi_logits (pure multi-stream, no
// dependent loads at all) and fuse the k-selection into the cdf loop with
// cndmask chains. NOTE: no runtime-indexed arrays anywhere (R1's scratch
// spill was dynamic row[k] indexing, not register pressure) -- all loop
// indices are compile-time after unrolling, so rows stay in VGPRs.
//
// Numerics mirror the JAX reference op-for-op (identical to the passing R2
// kernel): e_j = expf(l_j - max); S = sum(e) in order; cdf += e_j / S
// (per-element IEEE divide, no hoisted reciprocal); strict cdf < u.
// Selection equivalence: cdf is non-decreasing (e_j/S >= 0), so advancing
// the selected index whenever cdf_j < u (j = 0..K-2) yields exactly
// clip(#(cdf < u), 0, K-1); index K-1 is the max selectable (clip built in),
// and cdf_{K-1} is never needed (one fewer divide).

#define KMIX 10

__device__ __forceinline__ float sample_one(const float* __restrict__ lt,
                                            const float* __restrict__ mt,
                                            const float* __restrict__ st,
                                            float u, float ep) {
    float m = lt[0];
    #pragma unroll
    for (int j = 1; j < KMIX; ++j) m = fmaxf(m, lt[j]);

    float e[KMIX];
    float S = 0.f;
    #pragma unroll
    for (int j = 0; j < KMIX; ++j) {
        e[j] = expf(lt[j] - m);
        S += e[j];
    }

    float cdf = 0.f;
    float mk = mt[0];
    float sk = st[0];
    #pragma unroll
    for (int j = 0; j < KMIX - 1; ++j) {
        cdf += e[j] / S;            // per-element IEEE divide, matches reference
        bool take = (cdf < u);      // strict compare, matches reference
        mk = take ? mt[j + 1] : mk; // v_cndmask, compile-time index
        sk = take ? st[j + 1] : sk;
    }
    return mk + expf(sk) * ep;
}

__global__ __launch_bounds__(256, 2) void gmm_sample_kernel(
    const float* __restrict__ mu,
    const float* __restrict__ log_std,
    const float* __restrict__ pi_logits,
    const float* __restrict__ u_cat,
    const float* __restrict__ eps,
    float* __restrict__ out,
    int npairs)
{
    int p = blockIdx.x * blockDim.x + threadIdx.x;
    if (p >= npairs) return;

    size_t base = (size_t)p * (2 * KMIX);   // 80 B per row-pair -> 16 B aligned

    // Three row-pair streams: 5 x float4 each, all addresses affine in p.
    // Issue everything up front -- zero dependent loads in this kernel.
    const float4* pl4 = reinterpret_cast<const float4*>(pi_logits + base);
    const float4* mu4 = reinterpret_cast<const float4*>(mu + base);
    const float4* ls4 = reinterpret_cast<const float4*>(log_std + base);

    float l[2 * KMIX], mrow[2 * KMIX], srow[2 * KMIX];
    #pragma unroll
    for (int j = 0; j < 5; ++j) {
        float4 a = pl4[j];
        l[4 * j + 0] = a.x; l[4 * j + 1] = a.y;
        l[4 * j + 2] = a.z; l[4 * j + 3] = a.w;
    }
    #pragma unroll
    for (int j = 0; j < 5; ++j) {
        float4 a = mu4[j];
        mrow[4 * j + 0] = a.x; mrow[4 * j + 1] = a.y;
        mrow[4 * j + 2] = a.z; mrow[4 * j + 3] = a.w;
    }
    #pragma unroll
    for (int j = 0; j < 5; ++j) {
        float4 a = ls4[j];
        srow[4 * j + 0] = a.x; srow[4 * j + 1] = a.y;
        srow[4 * j + 2] = a.z; srow[4 * j + 3] = a.w;
    }
    float2 uu = *reinterpret_cast<const float2*>(u_cat + 2 * (size_t)p);
    float2 ee = *reinterpret_cast<const float2*>(eps + 2 * (size_t)p);

    float2 r;
    r.x = sample_one(l,        mrow,        srow,        uu.x, ee.x);
    r.y = sample_one(l + KMIX, mrow + KMIX, srow + KMIX, uu.y, ee.y);
    *reinterpret_cast<float2*>(out + 2 * (size_t)p) = r;
}

extern "C" void kernel_launch(void* const* d_in, const int* in_sizes, int n_in,
                              void* d_out, int out_size, void* d_ws, size_t ws_size,
                              hipStream_t stream) {
    const float* mu        = (const float*)d_in[0];
    const float* log_std   = (const float*)d_in[1];
    const float* pi_logits = (const float*)d_in[2];
    const float* u_cat     = (const float*)d_in[3];
    const float* eps       = (const float*)d_in[4];
    float* out = (float*)d_out;

    int N = in_sizes[3];          // B*F*T = 4,194,304 (even)
    int npairs = N / 2;
    int block = 256;
    int grid = (npairs + block - 1) / block;
    gmm_sample_kernel<<<grid, block, 0, stream>>>(mu, log_std, pi_logits,
                                                  u_cat, eps, out, npairs);
}

// Round 2
// 450.489 us; speedup vs baseline: 1.0087x; 1.0087x over previous
//
#include <hip/hip_runtime.h>
#include <math.h>

// GMM per-pixel sampling: out = mu[k] + exp(log_std[k]) * eps,
// k = #(cdf < u), cdf = cumsum(softmax(pi_logits)) over K=10 (innermost).
// Shapes [B,F,T,K] = [16,256,1024,10]; rows are 40 B.
//
// R4 structure: LDS-TRANSPOSED STAGING. R2 (row-pair float4 loads + global
// gather) and R3 (fully streamed row-pair loads) both pinned at ~155 us with
// VALUBusy ~20% and HBM ~28% -- the common factor is the 80 B lane stride on
// every large load (each wave-instr touches ~70 distinct 64 B lines with 16 B
// useful each; ~4-5x the TA/line transactions of a contiguous load).
// Here every global access is lane-contiguous 16 B (identical pattern to the
// 6.3 TB/s copy ubench): each 128-thread block stages its 256-pixel tile of
// all three arrays into LDS (30 KB) with coalesced float4 loads, issues all
// 15 loads in one burst (one memory round-trip per wave), then does the
// 80 B-stride reads and the mu[k]/log_std[k] gather FROM LDS where they are
// ~free. ds_read_b128 at stride-80: word-offsets 20*l mod 32 cover all 32
// banks once per 8 lanes -> 2-way on 16-lane phases = free (m136).
// All staging indices are compile-time after unroll (no scratch, rule #20).
//
// Numerics mirror the JAX reference op-for-op (identical to the passing R2
// kernel): e_j = expf(l_j - max); S = sum(e) in order; cdf += e_j / S
// (per-element IEEE divide, no hoisted reciprocal); strict cdf < u;
// k clipped to K-1.

#define KMIX 10
#define TPB 128                                   // 2 waves per block
#define PX_PER_BLOCK (TPB * 2)                    // 256 pixels per block
#define F_PER_ARRAY (PX_PER_BLOCK * KMIX)         // 2560 floats = 10,240 B
#define F4_PER_ARRAY (F_PER_ARRAY / 4)            // 640 float4

__device__ __forceinline__ int compute_k(const float* lt, float uval) {
    float m = lt[0];
    #pragma unroll
    for (int j = 1; j < KMIX; ++j) m = fmaxf(m, lt[j]);

    float e[KMIX];
    float S = 0.f;
    #pragma unroll
    for (int j = 0; j < KMIX; ++j) {
        e[j] = expf(lt[j] - m);
        S += e[j];
    }

    float cdf = 0.f;
    int k = 0;
    #pragma unroll
    for (int j = 0; j < KMIX; ++j) {
        cdf += e[j] / S;            // per-element IEEE divide, matches reference
        k += (cdf < uval) ? 1 : 0;  // strict compare, matches reference
    }
    return (k > KMIX - 1) ? (KMIX - 1) : k;   // jnp.clip(k, 0, K-1)
}

__global__ __launch_bounds__(TPB, 2) void gmm_sample_kernel(
    const float* __restrict__ mu,
    const float* __restrict__ log_std,
    const float* __restrict__ pi_logits,
    const float* __restrict__ u_cat,
    const float* __restrict__ eps,
    float* __restrict__ out,
    int npairs)
{
    __shared__ float4 s_pi4[F4_PER_ARRAY];
    __shared__ float4 s_mu4[F4_PER_ARRAY];
    __shared__ float4 s_ls4[F4_PER_ARRAY];

    const int tid = threadIdx.x;
    const size_t blk = blockIdx.x;
    const size_t base_f4 = blk * F4_PER_ARRAY;    // float4 index of block tile

    const float4* gpi = reinterpret_cast<const float4*>(pi_logits) + base_f4;
    const float4* gmu = reinterpret_cast<const float4*>(mu)        + base_f4;
    const float4* gls = reinterpret_cast<const float4*>(log_std)   + base_f4;

    // ---- Stage: issue ALL 15 coalesced loads first (static indices only),
    // then ds_write. Lane stride is 16 B -> each 64 B line fetched exactly
    // once by exactly one instruction.
    float4 t[15];
    #pragma unroll
    for (int j = 0; j < 5; ++j) t[j]      = gpi[j * TPB + tid];
    #pragma unroll
    for (int j = 0; j < 5; ++j) t[5 + j]  = gmu[j * TPB + tid];
    #pragma unroll
    for (int j = 0; j < 5; ++j) t[10 + j] = gls[j * TPB + tid];

    // Small per-thread streams (8 B/lane, already line-efficient).
    const size_t pair = blk * TPB + tid;          // pixel-pair index
    float2 uu = reinterpret_cast<const float2*>(u_cat)[pair];
    float2 ee = reinterpret_cast<const float2*>(eps)[pair];

    #pragma unroll
    for (int j = 0; j < 5; ++j) s_pi4[j * TPB + tid] = t[j];
    #pragma unroll
    for (int j = 0; j < 5; ++j) s_mu4[j * TPB + tid] = t[5 + j];
    #pragma unroll
    for (int j = 0; j < 5; ++j) s_ls4[j * TPB + tid] = t[10 + j];

    __syncthreads();

    // ---- Own row-pair from LDS: 80 B = 5 x ds_read_b128 at stride-80
    // (conflict-free per bank analysis above).
    float l[2 * KMIX];
    #pragma unroll
    for (int j = 0; j < 5; ++j) {
        float4 a = s_pi4[tid * 5 + j];
        l[4 * j + 0] = a.x; l[4 * j + 1] = a.y;
        l[4 * j + 2] = a.z; l[4 * j + 3] = a.w;
    }

    int k0 = compute_k(l, uu.x);
    int k1 = compute_k(l + KMIX, uu.y);

    // ---- Component gather from LDS (4 B reads; conflicts negligible).
    const float* s_mu = reinterpret_cast<const float*>(s_mu4);
    const float* s_ls = reinterpret_cast<const float*>(s_ls4);
    float mk0 = s_mu[20 * tid + k0];
    float sk0 = s_ls[20 * tid + k0];
    float mk1 = s_mu[20 * tid + KMIX + k1];
    float sk1 = s_ls[20 * tid + KMIX + k1];

    float2 r;
    r.x = mk0 + expf(sk0) * ee.x;
    r.y = mk1 + expf(sk1) * ee.y;
    if (pair < (size_t)npairs)
        reinterpret_cast<float2*>(out)[pair] = r;
}

extern "C" void kernel_launch(void* const* d_in, const int* in_sizes, int n_in,
                              void* d_out, int out_size, void* d_ws, size_t ws_size,
                              hipStream_t stream) {
    const float* mu        = (const float*)d_in[0];
    const float* log_std   = (const float*)d_in[1];
    const float* pi_logits = (const float*)d_in[2];
    const float* u_cat     = (const float*)d_in[3];
    const float* eps       = (const float*)d_in[4];
    float* out = (float*)d_out;

    int N = in_sizes[3];              // B*F*T = 4,194,304
    int npairs = N / 2;               // 2,097,152 = 16384 * 128 (exact)
    int grid = (npairs + TPB - 1) / TPB;
    gmm_sample_kernel<<<grid, TPB, 0, stream>>>(mu, log_std, pi_logits,
                                                u_cat, eps, out, npairs);
}